// Round 8
// baseline (552.414 us; speedup 1.0000x reference)
//
#include <hip/hip_runtime.h>
#include <hip/hip_cooperative_groups.h>
#include <math.h>

namespace cg = cooperative_groups;

#define LEAK 0.01f
#define BNEPS 1e-5f
#define NCH 256   // chunks for hist/scatter phases (256 blocks: keep grid wide)
#define NGMAX 1024
#define NSLOT 64  // BN partial slots

typedef __attribute__((ext_vector_type(8))) short bf16x8;
typedef __attribute__((ext_vector_type(4))) float f32x4;
typedef __attribute__((ext_vector_type(2))) float f32x2;
typedef unsigned int u32x2 __attribute__((ext_vector_type(2)));
typedef unsigned int u32x4 __attribute__((ext_vector_type(4)));

// ---------------- bf16 helpers ----------------
__device__ inline unsigned bfpack(float a, float b) {  // two f32 -> packed bf16 (RNE)
  unsigned ua = __float_as_uint(a);
  unsigned ub = __float_as_uint(b);
  unsigned ra = (ua + 0x7fffu + ((ua >> 16) & 1u)) >> 16;
  unsigned rb = (ub + 0x7fffu + ((ub >> 16) & 1u)) & 0xffff0000u;
  return ra | rb;
}
__device__ inline unsigned short bfround(float a) {
  unsigned ua = __float_as_uint(a);
  return (unsigned short)((ua + 0x7fffu + ((ua >> 16) & 1u)) >> 16);
}
__device__ inline float2 bfunpack(unsigned u) {
  float2 r;
  r.x = __uint_as_float(u << 16);
  r.y = __uint_as_float(u & 0xffff0000u);
  return r;
}
// fp8 e4m3 (OCP) helpers via gfx950 HW cvt
__device__ inline unsigned char f32_to_fp8(float v) {
  int p = __builtin_amdgcn_cvt_pk_fp8_f32(v, v, 0, false);
  return (unsigned char)(p & 0xff);
}

// =======================================================================
// CSR build, single cooperative kernel (was 6 dispatches).
// Phases separated by grid.sync(): hist -> chunk-sums -> exclusive scan ->
// local scan+offset -> bucket scatter -> per-bucket sort + rowptr/dinv.
// Grid = NCH (256) blocks = 1 block/CU (trivially co-resident).
// =======================================================================
__global__ __launch_bounds__(256) void k_csr(
    const int* __restrict__ src, const int* __restrict__ dst,
    int* __restrict__ H, int* __restrict__ hsum, int* __restrict__ O,
    int* __restrict__ ebuf, int* __restrict__ eidx, int* __restrict__ rowptr,
    float* __restrict__ dinv, float* __restrict__ invcnt,
    int E, int n, int NBK, int NBH, int MH) {
  cg::grid_group grid = cg::this_grid();
  __shared__ int s0[256], s1[256], s2[256];
  const int bid = blockIdx.x;
  const int t = threadIdx.x;
  const int chunk = (E + NCH - 1) / NCH;

  // ---- P1: per-chunk bucket histogram ----
  s0[t] = 0;
  __syncthreads();
  {
    int lo = bid * chunk, hi = min(lo + chunk, E);
    for (int e = lo + t; e < hi; e += 256) atomicAdd(&s0[dst[e] >> 8], 1);
  }
  __syncthreads();
  if (t < NBK) H[t * NCH + bid] = s0[t];
  grid.sync();

  // ---- P2: per-scan-block sums of H ----
  if (bid < NBH) {
    int i = bid * 256 + t;
    int v = (i < MH) ? H[i] : 0;
#pragma unroll
    for (int s = 1; s < 64; s <<= 1) v += __shfl_xor(v, s, 64);
    if ((t & 63) == 0) s1[t >> 6] = v;
    __syncthreads();
    if (t == 0) hsum[bid] = s1[0] + s1[1] + s1[2] + s1[3];
  }
  grid.sync();

  // ---- P3: exclusive scan of block sums (1 block) ----
  if (bid == 0) {
    int v = (t < NBH) ? hsum[t] : 0;
    s0[t] = v;
    __syncthreads();
    for (int ofs = 1; ofs < 256; ofs <<= 1) {
      int u = (t >= ofs) ? s0[t - ofs] : 0;
      __syncthreads();
      s0[t] += u;
      __syncthreads();
    }
    if (t < NBH) hsum[t] = s0[t] - v;
  }
  grid.sync();

  // ---- P4: local inclusive scan + block offset -> O ----
  if (bid < NBH) {
    int i = bid * 256 + t;
    int v = (i < MH) ? H[i] : 0;
    s0[t] = v;
    __syncthreads();
    for (int ofs = 1; ofs < 256; ofs <<= 1) {
      int u = (t >= ofs) ? s0[t - ofs] : 0;
      __syncthreads();
      s0[t] += u;
      __syncthreads();
    }
    if (i < MH) O[i] = hsum[bid] + s0[t] - v;
  }
  grid.sync();

  // ---- P5: scatter edges into dst-buckets ----
  if (t < NBK) s2[t] = O[t * NCH + bid];
  __syncthreads();
  {
    int lo = bid * chunk, hi = min(lo + chunk, E);
    for (int e = lo + t; e < hi; e += 256) {
      int d = dst[e];
      int pos = atomicAdd(&s2[d >> 8], 1);
      ebuf[pos] = src[e] | ((d & 255) << 24);   // requires n < 2^24
    }
  }
  grid.sync();

  // ---- P6: per-bucket counting sort + rowptr/dinv/invcnt ----
  if (bid < NBK) {
    const int lo = O[bid * NCH];
    const int hi2 = (bid + 1 < NBK) ? O[(bid + 1) * NCH] : E;
    s0[t] = 0;
    __syncthreads();
    for (int e = lo + t; e < hi2; e += 256)
      atomicAdd(&s0[(ebuf[e] >> 24) & 255], 1);
    __syncthreads();
    int v = s0[t];
    s1[t] = v;
    __syncthreads();
    for (int ofs = 1; ofs < 256; ofs <<= 1) {
      int u = (t >= ofs) ? s1[t - ofs] : 0;
      __syncthreads();
      s1[t] += u;
      __syncthreads();
    }
    int excl = s1[t] - v;
    s2[t] = lo + excl;
    int node = bid * 256 + t;
    if (node < n) {
      rowptr[node] = lo + excl;
      float d = (float)v;
      dinv[node]   = rsqrtf(d + 1.0f);
      invcnt[node] = 1.0f / fmaxf(d, 1.0f);
    }
    if (node == n || (bid == NBK - 1 && t == 255)) rowptr[n] = E;
    __syncthreads();
    for (int e = lo + t; e < hi2; e += 256) {
      int p = ebuf[e];
      int pos = atomicAdd(&s2[(p >> 24) & 255], 1);
      eidx[pos] = p & 0xFFFFFF;
    }
  }
}

// =======================================================================
// Unified CSR gather (one wave per node). FP8: neighbor rows fp8 e4m3,
// else bf16. GCN: + self (bf16) + bias. ADD: + addf (f32).
// STATS: per-block BN partial sums -> atomicAdd into 64-slot partials.
// POOL: atomicAdd output row into gpool[batch[v]] (no outb write).
// Row loads are NON-TEMPORAL (nt): random 1-use-per-miss lines thrash the
// 32KB L1; nt skips L1 allocation (L2/L3 policy per HW) to relieve the
// per-CU miss-handling path identified as the plateau across 4 structures.
// =======================================================================
template<int F, bool FP8, bool GCN, bool ADD, bool STATS, bool POOL>
__global__ __launch_bounds__(256) void k_gather(
    const void* __restrict__ Hn, const unsigned short* __restrict__ Hbf,
    const float* __restrict__ scale,
    const int* __restrict__ rowptr, const int* __restrict__ eidx,
    const float* __restrict__ bias, const float* __restrict__ addf,
    unsigned short* __restrict__ outb,
    float* __restrict__ partials, const int* __restrict__ batch,
    float* __restrict__ gpool, int n) {
  constexpr int COLS = F / 8;       // lanes per edge
  constexpr int EPI  = 64 / COLS;   // edges per iteration
  const int wid  = threadIdx.x >> 6;
  const int v    = blockIdx.x * 4 + wid;
  const bool valid = v < n;
  const int lane = threadIdx.x & 63;
  const int col  = lane % COLS;
  const int eo   = lane / COLS;

  const int lo = valid ? rowptr[v] : 0;
  const int hi = valid ? rowptr[v + 1] : 0;
  float a[8] = {0.f,0.f,0.f,0.f,0.f,0.f,0.f,0.f};
  int myE = (lo + lane < hi) ? eidx[lo + lane] : 0;
  for (int base = lo; base < hi; base += 64) {
    int cnt = min(hi - base, 64);
    int nxt = (base + 64 + lane < hi) ? eidx[base + 64 + lane] : 0;
#pragma unroll 4
    for (int t = eo; t < cnt; t += EPI) {
      int s = __shfl(myE, t, 64);
      if constexpr (FP8) {
        u32x2 q = __builtin_nontemporal_load(
            (const u32x2*)((const unsigned char*)Hn + (long long)s * F + col * 8));
        f32x2 p0 = __builtin_amdgcn_cvt_pk_f32_fp8(q[0], false);
        f32x2 p1 = __builtin_amdgcn_cvt_pk_f32_fp8(q[0], true);
        f32x2 p2 = __builtin_amdgcn_cvt_pk_f32_fp8(q[1], false);
        f32x2 p3 = __builtin_amdgcn_cvt_pk_f32_fp8(q[1], true);
        a[0]+=p0[0]; a[1]+=p0[1]; a[2]+=p1[0]; a[3]+=p1[1];
        a[4]+=p2[0]; a[5]+=p2[1]; a[6]+=p3[0]; a[7]+=p3[1];
      } else {
        u32x4 hv = __builtin_nontemporal_load(
            (const u32x4*)((const unsigned short*)Hn + (long long)s * F + col * 8));
        float2 p0 = bfunpack(hv[0]), p1 = bfunpack(hv[1]);
        float2 p2 = bfunpack(hv[2]), p3 = bfunpack(hv[3]);
        a[0]+=p0.x; a[1]+=p0.y; a[2]+=p1.x; a[3]+=p1.y;
        a[4]+=p2.x; a[5]+=p2.y; a[6]+=p3.x; a[7]+=p3.y;
      }
    }
    myE = nxt;
  }
#pragma unroll
  for (int m = COLS; m < 64; m <<= 1) {
#pragma unroll
    for (int j = 0; j < 8; j++) a[j] += __shfl_xor(a[j], m, 64);
  }

  float o[8] = {0.f,0.f,0.f,0.f,0.f,0.f,0.f,0.f};
  if (eo == 0 && valid) {
    float sv = scale[v];
    if constexpr (GCN) {
      uint4 hv = *(const uint4*)&Hbf[(long long)v * F + col * 8];
      float2 p0 = bfunpack(hv.x), p1 = bfunpack(hv.y);
      float2 p2 = bfunpack(hv.z), p3 = bfunpack(hv.w);
      float h[8] = {p0.x,p0.y,p1.x,p1.y,p2.x,p2.y,p3.x,p3.y};
#pragma unroll
      for (int j = 0; j < 8; j++) o[j] = bias[col * 8 + j] + sv * (a[j] + h[j]);
    } else if constexpr (ADD) {
      const float4 t0 = *(const float4*)&addf[(long long)v * F + col * 8];
      const float4 t1 = *(const float4*)&addf[(long long)v * F + col * 8 + 4];
      o[0]=fmaf(sv,a[0],t0.x); o[1]=fmaf(sv,a[1],t0.y);
      o[2]=fmaf(sv,a[2],t0.z); o[3]=fmaf(sv,a[3],t0.w);
      o[4]=fmaf(sv,a[4],t1.x); o[5]=fmaf(sv,a[5],t1.y);
      o[6]=fmaf(sv,a[6],t1.z); o[7]=fmaf(sv,a[7],t1.w);
    } else {
#pragma unroll
      for (int j = 0; j < 8; j++) o[j] = sv * a[j];
    }
    if constexpr (POOL) {
      int g = batch[v];
#pragma unroll
      for (int j = 0; j < 8; j++) atomicAdd(&gpool[(long long)g * F + col * 8 + j], o[j]);
    } else {
      uint4 u;
      u.x = bfpack(o[0], o[1]); u.y = bfpack(o[2], o[3]);
      u.z = bfpack(o[4], o[5]); u.w = bfpack(o[6], o[7]);
      *(uint4*)&outb[(long long)v * F + col * 8] = u;
    }
  }

  if constexpr (STATS) {
    __shared__ float sred[4][2 * F];
    if (eo == 0) {
#pragma unroll
      for (int j = 0; j < 8; j++) {
        sred[wid][col * 8 + j]     = o[j];
        sred[wid][F + col * 8 + j] = o[j] * o[j];
      }
    }
    __syncthreads();
    int t = threadIdx.x;
    if (t < 2 * F) {
      float s = sred[0][t] + sred[1][t] + sred[2][t] + sred[3][t];
      atomicAdd(&partials[((int)blockIdx.x & (NSLOT - 1)) * 2 * F + t], s);
    }
  }
}

// =======================================================================
// MFMA GEMM: Yb = bf16(prescale * (act(X) @ W)); optional fp8 copy (F8OUT).
// BNIN: finalize BN stats from 64-slot partials in-prologue (redundant per
// block; partials are L2-hot). All: grid-stride zero of zptr (preps the
// partials/gpool buffer for the NEXT kernel in the chain).
// =======================================================================
template<int K, int F, bool XBF, bool BNIN, bool F8OUT>
__global__ __launch_bounds__(256) void k_gemm_mfma(
    const void* __restrict__ Xv, const float* __restrict__ W,
    const float* __restrict__ pin, const float* __restrict__ gw,
    const float* __restrict__ bw, float invN,
    const float* __restrict__ prescale,
    unsigned short* __restrict__ Yb, unsigned char* __restrict__ Yf8,
    float* __restrict__ zptr, int zcnt, int n) {
  constexpr int SP  = K + 8;      // padded LDS row stride (shorts)
  constexpr int NCT = F / 16;     // col-tiles per wave
  __shared__ unsigned short sX[64 * SP];
  __shared__ unsigned short sWT[F * SP];
  __shared__ float sbn[BNIN ? 2 * K : 1];

  // zero next-stage accumulator buffer (visible at next kernel launch)
  for (int i = blockIdx.x * 256 + threadIdx.x; i < zcnt; i += gridDim.x * 256)
    zptr[i] = 0.f;

  const int row0 = blockIdx.x * 64;
  if constexpr (BNIN) {
    int t = threadIdx.x;
    if (t < K) {
      float s1 = 0.f, s2 = 0.f;
      for (int s = 0; s < NSLOT; s++) {
        s1 += pin[s * 2 * K + t];
        s2 += pin[s * 2 * K + K + t];
      }
      float m   = s1 * invN;
      float var = s2 * invN - m * m;
      float scv = gw[t] * rsqrtf(var + BNEPS);
      sbn[t]     = scv;
      sbn[K + t] = bw[t] - m * scv;
    }
    __syncthreads();
  }
  for (int i = threadIdx.x; i < (K / 2) * F; i += 256) {
    int nn = i % F;
    int kk = (i / F) * 2;
    float w0 = W[(long long)kk * F + nn];
    float w1 = W[(long long)(kk + 1) * F + nn];
    *(unsigned*)&sWT[nn * SP + kk] = bfpack(w0, w1);
  }
  for (int i = threadIdx.x; i < 64 * (K / 8); i += 256) {
    int r = i / (K / 8), k8 = (i % (K / 8)) * 8;
    int gr = row0 + r;
    uint4 u = {0, 0, 0, 0};
    if (gr < n) {
      if constexpr (XBF) {
        const unsigned short* X = (const unsigned short*)Xv;
        uint4 raw = *(const uint4*)&X[(long long)gr * K + k8];
        if constexpr (BNIN) {
          float2 p0 = bfunpack(raw.x), p1 = bfunpack(raw.y);
          float2 p2 = bfunpack(raw.z), p3 = bfunpack(raw.w);
          float y[8] = {p0.x,p0.y,p1.x,p1.y,p2.x,p2.y,p3.x,p3.y};
#pragma unroll
          for (int j = 0; j < 8; j++) {
            float t = fmaf(y[j], sbn[k8 + j], sbn[K + k8 + j]);
            y[j] = (t >= 0.f) ? t : LEAK * t;
          }
          u.x = bfpack(y[0], y[1]); u.y = bfpack(y[2], y[3]);
          u.z = bfpack(y[4], y[5]); u.w = bfpack(y[6], y[7]);
        } else {
          u = raw;
        }
      } else {
        const float* X = (const float*)Xv;
        float4 xa = *(const float4*)&X[(long long)gr * K + k8];
        float4 xb = *(const float4*)&X[(long long)gr * K + k8 + 4];
        u.x = bfpack(xa.x, xa.y); u.y = bfpack(xa.z, xa.w);
        u.z = bfpack(xb.x, xb.y); u.w = bfpack(xb.z, xb.w);
      }
    }
    *(uint4*)&sX[r * SP + k8] = u;
  }
  __syncthreads();

  const int wv   = threadIdx.x >> 6;
  const int lane = threadIdx.x & 63;
  const int l16  = lane & 15;
  const int quad = lane >> 4;
  f32x4 acc[NCT];
#pragma unroll
  for (int c = 0; c < NCT; c++) acc[c] = (f32x4){0.f, 0.f, 0.f, 0.f};

#pragma unroll
  for (int k0 = 0; k0 < K; k0 += 32) {
    bf16x8 af = *(const bf16x8*)&sX[(wv * 16 + l16) * SP + k0 + quad * 8];
#pragma unroll
    for (int c = 0; c < NCT; c++) {
      bf16x8 bfr = *(const bf16x8*)&sWT[(c * 16 + l16) * SP + k0 + quad * 8];
      acc[c] = __builtin_amdgcn_mfma_f32_16x16x32_bf16(af, bfr, acc[c], 0, 0, 0);
    }
  }

  const int rbase = row0 + wv * 16 + quad * 4;
  float ps[4];
#pragma unroll
  for (int rg = 0; rg < 4; rg++) {
    int gr = rbase + rg;
    ps[rg] = (prescale && gr < n) ? prescale[gr] : 1.0f;
  }
#pragma unroll
  for (int c = 0; c < NCT; c++) {
    int col = c * 16 + l16;
#pragma unroll
    for (int rg = 0; rg < 4; rg++) {
      int gr = rbase + rg;
      if (gr < n) {
        float val = acc[c][rg] * ps[rg];
        Yb[(long long)gr * F + col] = bfround(val);
        if constexpr (F8OUT) Yf8[(long long)gr * F + col] = f32_to_fp8(val);
      }
    }
  }
}

// ==== SAGE dual MFMA GEMM (BN1+lrelu fused): t1=X'@Wl fp8, t2=X'@Wr+bl f32 ===
__global__ __launch_bounds__(256) void k_gemm_sage_mfma(
    const unsigned short* __restrict__ X, const float* __restrict__ Wl,
    const float* __restrict__ Wr, const float* __restrict__ bl,
    const float* __restrict__ pin, const float* __restrict__ gw,
    const float* __restrict__ bw, float invN,
    unsigned char* __restrict__ t1f8, float* __restrict__ t2,
    float* __restrict__ zptr, int zcnt, int n) {
  constexpr int K = 128, F = 64, SP = K + 8, NCT = F / 16;  // 4
  __shared__ unsigned short sX[64 * SP];
  __shared__ unsigned short sWlT[F * SP];
  __shared__ unsigned short sWrT[F * SP];
  __shared__ float sbn[2 * K];

  for (int i = blockIdx.x * 256 + threadIdx.x; i < zcnt; i += gridDim.x * 256)
    zptr[i] = 0.f;

  {
    int t = threadIdx.x;
    if (t < K) {
      float s1 = 0.f, s2 = 0.f;
      for (int s = 0; s < NSLOT; s++) {
        s1 += pin[s * 2 * K + t];
        s2 += pin[s * 2 * K + K + t];
      }
      float m   = s1 * invN;
      float var = s2 * invN - m * m;
      float scv = gw[t] * rsqrtf(var + BNEPS);
      sbn[t]     = scv;
      sbn[K + t] = bw[t] - m * scv;
    }
  }
  __syncthreads();
  const int row0 = blockIdx.x * 64;
  for (int i = threadIdx.x; i < (K / 2) * F; i += 256) {
    int nn = i % F;
    int kk = (i / F) * 2;
    *(unsigned*)&sWlT[nn * SP + kk] =
        bfpack(Wl[(long long)kk * F + nn], Wl[(long long)(kk + 1) * F + nn]);
    *(unsigned*)&sWrT[nn * SP + kk] =
        bfpack(Wr[(long long)kk * F + nn], Wr[(long long)(kk + 1) * F + nn]);
  }
  for (int i = threadIdx.x; i < 64 * (K / 8); i += 256) {
    int r = i / (K / 8), k8 = (i % (K / 8)) * 8;
    int gr = row0 + r;
    uint4 u = {0, 0, 0, 0};
    if (gr < n) {
      uint4 raw = *(const uint4*)&X[(long long)gr * K + k8];
      float2 p0 = bfunpack(raw.x), p1 = bfunpack(raw.y);
      float2 p2 = bfunpack(raw.z), p3 = bfunpack(raw.w);
      float y[8] = {p0.x,p0.y,p1.x,p1.y,p2.x,p2.y,p3.x,p3.y};
#pragma unroll
      for (int j = 0; j < 8; j++) {
        float t = fmaf(y[j], sbn[k8 + j], sbn[K + k8 + j]);
        y[j] = (t >= 0.f) ? t : LEAK * t;
      }
      u.x = bfpack(y[0], y[1]); u.y = bfpack(y[2], y[3]);
      u.z = bfpack(y[4], y[5]); u.w = bfpack(y[6], y[7]);
    }
    *(uint4*)&sX[r * SP + k8] = u;
  }
  __syncthreads();

  const int wv   = threadIdx.x >> 6;
  const int lane = threadIdx.x & 63;
  const int l16  = lane & 15;
  const int quad = lane >> 4;
  f32x4 a1[NCT], a2[NCT];
#pragma unroll
  for (int c = 0; c < NCT; c++) {
    a1[c] = (f32x4){0.f, 0.f, 0.f, 0.f};
    a2[c] = (f32x4){0.f, 0.f, 0.f, 0.f};
  }
#pragma unroll
  for (int k0 = 0; k0 < K; k0 += 32) {
    bf16x8 af = *(const bf16x8*)&sX[(wv * 16 + l16) * SP + k0 + quad * 8];
#pragma unroll
    for (int c = 0; c < NCT; c++) {
      bf16x8 bl8 = *(const bf16x8*)&sWlT[(c * 16 + l16) * SP + k0 + quad * 8];
      bf16x8 br8 = *(const bf16x8*)&sWrT[(c * 16 + l16) * SP + k0 + quad * 8];
      a1[c] = __builtin_amdgcn_mfma_f32_16x16x32_bf16(af, bl8, a1[c], 0, 0, 0);
      a2[c] = __builtin_amdgcn_mfma_f32_16x16x32_bf16(af, br8, a2[c], 0, 0, 0);
    }
  }
  const int rbase = row0 + wv * 16 + quad * 4;
#pragma unroll
  for (int c = 0; c < NCT; c++) {
    int col = c * 16 + l16;
    float blv = bl[col];
#pragma unroll
    for (int rg = 0; rg < 4; rg++) {
      int gr = rbase + rg;
      if (gr < n) {
        t1f8[(long long)gr * F + col] = f32_to_fp8(a1[c][rg]);
        t2[(long long)gr * F + col]   = a2[c][rg] + blv;
      }
    }
  }
}

// ---------------- link predictor ----------------
__global__ void k_link(const float* __restrict__ g, const int* __restrict__ li0,
                       const int* __restrict__ li1, float* __restrict__ out, int L) {
  int i = blockIdx.x * blockDim.x + threadIdx.x;
  if (i >= L) return;
  const float* a = g + (long long)li0[i] * 32;
  const float* b = g + (long long)li1[i] * 32;
  float s = 0.f;
#pragma unroll
  for (int f = 0; f < 32; f++) s = fmaf(a[f], b[f], s);
  out[i] = 1.0f / (1.0f + expf(-s));
}

// ---------------- launch ----------------
extern "C" void kernel_launch(void* const* d_in, const int* in_sizes, int n_in,
                              void* d_out, int out_size, void* d_ws, size_t ws_size,
                              hipStream_t stream) {
  const float* x   = (const float*)d_in[0];
  const int* ei    = (const int*)d_in[1];
  const int* batch = (const int*)d_in[2];
  const int* li    = (const int*)d_in[3];
  const float* W1  = (const float*)d_in[5];
  const float* b1  = (const float*)d_in[6];
  const float* g1  = (const float*)d_in[7];
  const float* be1 = (const float*)d_in[8];
  const float* Wl2 = (const float*)d_in[9];
  const float* bl2 = (const float*)d_in[10];
  const float* Wr2 = (const float*)d_in[11];
  const float* g2  = (const float*)d_in[12];
  const float* be2 = (const float*)d_in[13];
  const float* W3  = (const float*)d_in[14];
  const float* b3  = (const float*)d_in[15];
  const float* g3  = (const float*)d_in[16];
  const float* be3 = (const float*)d_in[17];
  const float* W4  = (const float*)d_in[18];
  const float* b4  = (const float*)d_in[19];

  const int n = in_sizes[0] / 128;   // 50000
  const int E = in_sizes[1] / 2;     // 800000
  const int L = in_sizes[3] / 2;     // 1000
  const int* src = ei;
  const int* dst = ei + E;
  const int* li0 = li;
  const int* li1 = li + L;
  const int NBK = (n + 255) / 256;   // dst buckets (<=256 for n<=65536)

  char* base = (char*)d_ws;
  size_t off = 0;
  auto alloc = [&](size_t bytes) -> void* {
    void* p = (void*)(base + off);
    off = (off + bytes + 255) & ~(size_t)255;
    return p;
  };
  int*   H      = (int*)alloc((size_t)NBK * NCH * 4);
  int*   O      = (int*)alloc((size_t)NBK * NCH * 4);
  int*   hsum   = (int*)alloc((size_t)1024 * 4);
  int*   ebuf   = (int*)alloc((size_t)E * 4);
  int*   eidx   = (int*)alloc((size_t)E * 4);
  int*   rowptr = (int*)alloc((size_t)(n + 1) * 4);
  float* dinv   = (float*)alloc((size_t)n * 4);
  float* invcnt = (float*)alloc((size_t)n * 4);
  float* partials1 = (float*)alloc((size_t)NSLOT * 256 * 4);  // layer1: 2F=256
  float* partials2 = (float*)alloc((size_t)NSLOT * 128 * 4);  // layer2: 2F=128
  float* partials3 = (float*)alloc((size_t)NSLOT * 64 * 4);   // layer3: 2F=64
  float* gpool  = (float*)alloc((size_t)NGMAX * 32 * 4);
  unsigned short* h1b  = (unsigned short*)alloc((size_t)n * 128 * 2); // dinv*(x@W1) bf16
  unsigned char*  h1f8 = (unsigned char*)alloc((size_t)n * 128);     // same, fp8 e4m3
  unsigned short* a1b  = (unsigned short*)alloc((size_t)n * 128 * 2); // pre-BN a1
  unsigned char*  t1f8 = (unsigned char*)alloc((size_t)n * 64);      // h1'@Wl2 fp8
  float*          t2f  = (float*)alloc((size_t)n * 64 * 4);          // h1'@Wr2+bl2
  unsigned short* h2b  = (unsigned short*)alloc((size_t)n * 64 * 2); // pre-BN h2
  unsigned short* h3gb = (unsigned short*)alloc((size_t)n * 32 * 2); // dinv*(h2'@W3)
  unsigned short* a3b  = (unsigned short*)alloc((size_t)n * 32 * 2); // pre-BN a3
  unsigned short* h4b  = (unsigned short*)alloc((size_t)n * 32 * 2); // dinv*(h3'@W4)
  (void)ws_size; (void)n_in; (void)out_size;

  const int BT = 256;
  auto cdiv = [](long long a, long long b) { return (int)((a + b - 1) / b); };
  const int GB  = cdiv(n, 4);                 // gather grid
  const int GM  = cdiv(n, 64);                // mfma gemm grid
  const int MH  = NBK * NCH;                  // histogram elements
  const int NBH = cdiv(MH, 256);              // scan blocks
  const float invN = 1.0f / (float)n;

  // ---- CSR build: single cooperative kernel (was 6 dispatches) ----
  {
    int E_ = E, n_ = n, NBK_ = NBK, NBH_ = NBH, MH_ = MH;
    void* kargs[] = {
      (void*)&src, (void*)&dst, (void*)&H, (void*)&hsum, (void*)&O,
      (void*)&ebuf, (void*)&eidx, (void*)&rowptr, (void*)&dinv, (void*)&invcnt,
      (void*)&E_, (void*)&n_, (void*)&NBK_, (void*)&NBH_, (void*)&MH_
    };
    hipLaunchCooperativeKernel((void*)k_csr, dim3(NCH), dim3(256), kargs, 0, stream);
  }

  // ---- L1: GCN 128->128 (MFMA; emits bf16 + fp8; zeroes partials1) ----
  k_gemm_mfma<128,128,false,false,true><<<GM, 256, 0, stream>>>(
      x, W1, nullptr, nullptr, nullptr, 0.f, dinv, h1b, h1f8,
      partials1, NSLOT * 256, n);
  k_gather<128,true,true,false,true,false><<<GB, 256, 0, stream>>>(
      h1f8, h1b, dinv, rowptr, eidx, b1, nullptr, a1b,
      partials1, nullptr, nullptr, n);

  // ---- L2: SAGE 128->64 (MFMA dual; BN1 finalized in-prologue) ----
  k_gemm_sage_mfma<<<GM, 256, 0, stream>>>(
      a1b, Wl2, Wr2, bl2, partials1, g1, be1, invN, t1f8, t2f,
      partials2, NSLOT * 128, n);
  k_gather<64,true,false,true,true,false><<<GB, 256, 0, stream>>>(
      t1f8, nullptr, invcnt, rowptr, eidx, nullptr, t2f, h2b,
      partials2, nullptr, nullptr, n);

  // ---- L3: GCN 64->32 (MFMA; BN2 finalized in-prologue) ----
  k_gemm_mfma<64,32,true,true,false><<<GM, 256, 0, stream>>>(
      h2b, W3, partials2, g2, be2, invN, dinv, h3gb, nullptr,
      partials3, NSLOT * 64, n);
  k_gather<32,false,true,false,true,false><<<GB, 256, 0, stream>>>(
      h3gb, h3gb, dinv, rowptr, eidx, b3, nullptr, a3b,
      partials3, nullptr, nullptr, n);

  // ---- L4: GCN 32->32 (MFMA; BN3 finalized in-prologue; zeroes gpool),
  //      gather pools directly via atomics into gpool ----
  k_gemm_mfma<32,32,true,true,false><<<GM, 256, 0, stream>>>(
      a3b, W4, partials3, g3, be3, invN, dinv, h4b, nullptr,
      gpool, NGMAX * 32, n);
  k_gather<32,false,true,false,false,true><<<GB, 256, 0, stream>>>(
      h4b, h4b, dinv, rowptr, eidx, b4, nullptr, nullptr,
      nullptr, batch, gpool, n);

  // ---- link ----
  k_link<<<cdiv(L, BT), BT, 0, stream>>>(gpool, li0, li1, (float*)d_out, L);
}

// Round 9
// 355.424 us; speedup vs baseline: 1.5542x; 1.5542x over previous
//
#include <hip/hip_runtime.h>
#include <math.h>

#define LEAK 0.01f
#define BNEPS 1e-5f
#define NCH 256   // chunks for hist/scatter phases (256 blocks: keep grid wide)
#define NGMAX 1024
#define NSLOT 64  // BN partial slots

typedef __attribute__((ext_vector_type(8))) short bf16x8;
typedef __attribute__((ext_vector_type(4))) float f32x4;
typedef __attribute__((ext_vector_type(2))) float f32x2;

// ---------------- bf16 helpers ----------------
__device__ inline unsigned bfpack(float a, float b) {  // two f32 -> packed bf16 (RNE)
  unsigned ua = __float_as_uint(a);
  unsigned ub = __float_as_uint(b);
  unsigned ra = (ua + 0x7fffu + ((ua >> 16) & 1u)) >> 16;
  unsigned rb = (ub + 0x7fffu + ((ub >> 16) & 1u)) & 0xffff0000u;
  return ra | rb;
}
__device__ inline unsigned short bfround(float a) {
  unsigned ua = __float_as_uint(a);
  return (unsigned short)((ua + 0x7fffu + ((ua >> 16) & 1u)) >> 16);
}
__device__ inline float2 bfunpack(unsigned u) {
  float2 r;
  r.x = __uint_as_float(u << 16);
  r.y = __uint_as_float(u & 0xffff0000u);
  return r;
}
// fp8 e4m3 (OCP) helpers via gfx950 HW cvt
__device__ inline unsigned char f32_to_fp8(float v) {
  int p = __builtin_amdgcn_cvt_pk_fp8_f32(v, v, 0, false);
  return (unsigned char)(p & 0xff);
}

// =======================================================================
// CSR build via bucketed counting sort (bucket = dst>>8, NBK<=256)
// =======================================================================
__global__ __launch_bounds__(256) void k_hist(const int* __restrict__ dst,
                                              int* __restrict__ H, int E, int NBK) {
  __shared__ int h[256];
  h[threadIdx.x] = 0;
  __syncthreads();
  int chunk = (E + NCH - 1) / NCH;
  int lo = blockIdx.x * chunk, hi = min(lo + chunk, E);
  for (int e = lo + threadIdx.x; e < hi; e += 256)
    atomicAdd(&h[dst[e] >> 8], 1);
  __syncthreads();
  if (threadIdx.x < NBK) H[threadIdx.x * NCH + blockIdx.x] = h[threadIdx.x];
}

__global__ __launch_bounds__(256) void k_gscan1(const int* __restrict__ in,
                                                int* __restrict__ bsum, int m) {
  int i = blockIdx.x * 256 + threadIdx.x;
  int v = (i < m) ? in[i] : 0;
#pragma unroll
  for (int s = 1; s < 64; s <<= 1) v += __shfl_xor(v, s, 64);
  __shared__ int ws[4];
  if ((threadIdx.x & 63) == 0) ws[threadIdx.x >> 6] = v;
  __syncthreads();
  if (threadIdx.x == 0) bsum[blockIdx.x] = ws[0] + ws[1] + ws[2] + ws[3];
}
__global__ __launch_bounds__(256) void k_gscan2(int* __restrict__ bsum, int NB) {
  __shared__ int lds[256];
  int t = threadIdx.x;
  int v = (t < NB) ? bsum[t] : 0;
  lds[t] = v;
  __syncthreads();
  for (int ofs = 1; ofs < 256; ofs <<= 1) {
    int u = (t >= ofs) ? lds[t - ofs] : 0;
    __syncthreads();
    lds[t] += u;
    __syncthreads();
  }
  if (t < NB) bsum[t] = lds[t] - v;  // exclusive, in-place
}
__global__ __launch_bounds__(256) void k_gscan3(const int* __restrict__ in,
                                                const int* __restrict__ boff,
                                                int* __restrict__ out, int m) {
  __shared__ int lds[256];
  int t = threadIdx.x;
  int i = blockIdx.x * 256 + t;
  int v = (i < m) ? in[i] : 0;
  lds[t] = v;
  __syncthreads();
  for (int ofs = 1; ofs < 256; ofs <<= 1) {
    int u = (t >= ofs) ? lds[t - ofs] : 0;
    __syncthreads();
    lds[t] += u;
    __syncthreads();
  }
  if (i < m) out[i] = boff[blockIdx.x] + lds[t] - v;
}

__global__ __launch_bounds__(256) void k_scatter_bkt(
    const int* __restrict__ src, const int* __restrict__ dst,
    const int* __restrict__ O, int* __restrict__ ebuf, int E, int NBK) {
  __shared__ int cur[256];
  if (threadIdx.x < NBK) cur[threadIdx.x] = O[threadIdx.x * NCH + blockIdx.x];
  __syncthreads();
  int chunk = (E + NCH - 1) / NCH;
  int lo = blockIdx.x * chunk, hi = min(lo + chunk, E);
  for (int e = lo + threadIdx.x; e < hi; e += 256) {
    int d = dst[e];
    int pos = atomicAdd(&cur[d >> 8], 1);
    ebuf[pos] = src[e] | ((d & 255) << 24);   // requires n < 2^24
  }
}

__global__ __launch_bounds__(256) void k_fill2(
    const int* __restrict__ ebuf, const int* __restrict__ O,
    int* __restrict__ eidx, int* __restrict__ rowptr,
    float* __restrict__ dinv, float* __restrict__ invcnt,
    int E, int n, int NBK) {
  __shared__ int hist[256];
  __shared__ int sc[256];
  __shared__ int cur[256];
  const int b = blockIdx.x;
  const int t = threadIdx.x;
  const int lo = O[b * NCH];
  const int hi = (b + 1 < NBK) ? O[(b + 1) * NCH] : E;
  hist[t] = 0;
  __syncthreads();
  for (int e = lo + t; e < hi; e += 256)
    atomicAdd(&hist[(ebuf[e] >> 24) & 255], 1);
  __syncthreads();
  int v = hist[t];
  sc[t] = v;
  __syncthreads();
  for (int ofs = 1; ofs < 256; ofs <<= 1) {
    int u = (t >= ofs) ? sc[t - ofs] : 0;
    __syncthreads();
    sc[t] += u;
    __syncthreads();
  }
  int excl = sc[t] - v;
  cur[t] = lo + excl;
  int node = b * 256 + t;
  if (node < n) {
    rowptr[node] = lo + excl;
    float d = (float)v;
    dinv[node]   = rsqrtf(d + 1.0f);
    invcnt[node] = 1.0f / fmaxf(d, 1.0f);
  }
  if (node == n || (b == NBK - 1 && t == 255)) rowptr[n] = E;
  __syncthreads();
  for (int e = lo + t; e < hi; e += 256) {
    int p = ebuf[e];
    int pos = atomicAdd(&cur[(p >> 24) & 255], 1);
    eidx[pos] = p & 0xFFFFFF;
  }
}

// =======================================================================
// Unified CSR gather (one wave per node). FP8: neighbor rows fp8 e4m3,
// else bf16. GCN: + self (bf16) + bias. ADD: + addf (f32).
// STATS: per-block BN partial sums -> atomicAdd into 64-slot partials.
// POOL: atomicAdd output row into gpool[batch[v]] (no outb write).
// =======================================================================
template<int F, bool FP8, bool GCN, bool ADD, bool STATS, bool POOL>
__global__ __launch_bounds__(256) void k_gather(
    const void* __restrict__ Hn, const unsigned short* __restrict__ Hbf,
    const float* __restrict__ scale,
    const int* __restrict__ rowptr, const int* __restrict__ eidx,
    const float* __restrict__ bias, const float* __restrict__ addf,
    unsigned short* __restrict__ outb,
    float* __restrict__ partials, const int* __restrict__ batch,
    float* __restrict__ gpool, int n) {
  constexpr int COLS = F / 8;       // lanes per edge
  constexpr int EPI  = 64 / COLS;   // edges per iteration
  const int wid  = threadIdx.x >> 6;
  const int v    = blockIdx.x * 4 + wid;
  const bool valid = v < n;
  const int lane = threadIdx.x & 63;
  const int col  = lane % COLS;
  const int eo   = lane / COLS;

  const int lo = valid ? rowptr[v] : 0;
  const int hi = valid ? rowptr[v + 1] : 0;
  float a[8] = {0.f,0.f,0.f,0.f,0.f,0.f,0.f,0.f};
  int myE = (lo + lane < hi) ? eidx[lo + lane] : 0;
  for (int base = lo; base < hi; base += 64) {
    int cnt = min(hi - base, 64);
    int nxt = (base + 64 + lane < hi) ? eidx[base + 64 + lane] : 0;
#pragma unroll 4
    for (int t = eo; t < cnt; t += EPI) {
      int s = __shfl(myE, t, 64);
      if constexpr (FP8) {
        uint2 q = *(const uint2*)((const unsigned char*)Hn + (long long)s * F + col * 8);
        f32x2 p0 = __builtin_amdgcn_cvt_pk_f32_fp8(q.x, false);
        f32x2 p1 = __builtin_amdgcn_cvt_pk_f32_fp8(q.x, true);
        f32x2 p2 = __builtin_amdgcn_cvt_pk_f32_fp8(q.y, false);
        f32x2 p3 = __builtin_amdgcn_cvt_pk_f32_fp8(q.y, true);
        a[0]+=p0[0]; a[1]+=p0[1]; a[2]+=p1[0]; a[3]+=p1[1];
        a[4]+=p2[0]; a[5]+=p2[1]; a[6]+=p3[0]; a[7]+=p3[1];
      } else {
        uint4 hv = *(const uint4*)((const unsigned short*)Hn + (long long)s * F + col * 8);
        float2 p0 = bfunpack(hv.x), p1 = bfunpack(hv.y);
        float2 p2 = bfunpack(hv.z), p3 = bfunpack(hv.w);
        a[0]+=p0.x; a[1]+=p0.y; a[2]+=p1.x; a[3]+=p1.y;
        a[4]+=p2.x; a[5]+=p2.y; a[6]+=p3.x; a[7]+=p3.y;
      }
    }
    myE = nxt;
  }
#pragma unroll
  for (int m = COLS; m < 64; m <<= 1) {
#pragma unroll
    for (int j = 0; j < 8; j++) a[j] += __shfl_xor(a[j], m, 64);
  }

  float o[8] = {0.f,0.f,0.f,0.f,0.f,0.f,0.f,0.f};
  if (eo == 0 && valid) {
    float sv = scale[v];
    if constexpr (GCN) {
      uint4 hv = *(const uint4*)&Hbf[(long long)v * F + col * 8];
      float2 p0 = bfunpack(hv.x), p1 = bfunpack(hv.y);
      float2 p2 = bfunpack(hv.z), p3 = bfunpack(hv.w);
      float h[8] = {p0.x,p0.y,p1.x,p1.y,p2.x,p2.y,p3.x,p3.y};
#pragma unroll
      for (int j = 0; j < 8; j++) o[j] = bias[col * 8 + j] + sv * (a[j] + h[j]);
    } else if constexpr (ADD) {
      const float4 t0 = *(const float4*)&addf[(long long)v * F + col * 8];
      const float4 t1 = *(const float4*)&addf[(long long)v * F + col * 8 + 4];
      o[0]=fmaf(sv,a[0],t0.x); o[1]=fmaf(sv,a[1],t0.y);
      o[2]=fmaf(sv,a[2],t0.z); o[3]=fmaf(sv,a[3],t0.w);
      o[4]=fmaf(sv,a[4],t1.x); o[5]=fmaf(sv,a[5],t1.y);
      o[6]=fmaf(sv,a[6],t1.z); o[7]=fmaf(sv,a[7],t1.w);
    } else {
#pragma unroll
      for (int j = 0; j < 8; j++) o[j] = sv * a[j];
    }
    if constexpr (POOL) {
      int g = batch[v];
#pragma unroll
      for (int j = 0; j < 8; j++) atomicAdd(&gpool[(long long)g * F + col * 8 + j], o[j]);
    } else {
      uint4 u;
      u.x = bfpack(o[0], o[1]); u.y = bfpack(o[2], o[3]);
      u.z = bfpack(o[4], o[5]); u.w = bfpack(o[6], o[7]);
      *(uint4*)&outb[(long long)v * F + col * 8] = u;
    }
  }

  if constexpr (STATS) {
    __shared__ float sred[4][2 * F];
    if (eo == 0) {
#pragma unroll
      for (int j = 0; j < 8; j++) {
        sred[wid][col * 8 + j]     = o[j];
        sred[wid][F + col * 8 + j] = o[j] * o[j];
      }
    }
    __syncthreads();
    int t = threadIdx.x;
    if (t < 2 * F) {
      float s = sred[0][t] + sred[1][t] + sred[2][t] + sred[3][t];
      atomicAdd(&partials[((int)blockIdx.x & (NSLOT - 1)) * 2 * F + t], s);
    }
  }
}

// =======================================================================
// MFMA GEMM: Yb = bf16(prescale * (act(X) @ W)); optional fp8 copy (F8OUT).
// BNIN: finalize BN stats from 64-slot partials in-prologue (redundant per
// block; partials are L2-hot). All: grid-stride zero of zptr (preps the
// partials/gpool buffer for the NEXT kernel in the chain).
// =======================================================================
template<int K, int F, bool XBF, bool BNIN, bool F8OUT>
__global__ __launch_bounds__(256) void k_gemm_mfma(
    const void* __restrict__ Xv, const float* __restrict__ W,
    const float* __restrict__ pin, const float* __restrict__ gw,
    const float* __restrict__ bw, float invN,
    const float* __restrict__ prescale,
    unsigned short* __restrict__ Yb, unsigned char* __restrict__ Yf8,
    float* __restrict__ zptr, int zcnt, int n) {
  constexpr int SP  = K + 8;      // padded LDS row stride (shorts)
  constexpr int NCT = F / 16;     // col-tiles per wave
  __shared__ unsigned short sX[64 * SP];
  __shared__ unsigned short sWT[F * SP];
  __shared__ float sbn[BNIN ? 2 * K : 1];

  // zero next-stage accumulator buffer (visible at next kernel launch)
  for (int i = blockIdx.x * 256 + threadIdx.x; i < zcnt; i += gridDim.x * 256)
    zptr[i] = 0.f;

  const int row0 = blockIdx.x * 64;
  if constexpr (BNIN) {
    int t = threadIdx.x;
    if (t < K) {
      float s1 = 0.f, s2 = 0.f;
      for (int s = 0; s < NSLOT; s++) {
        s1 += pin[s * 2 * K + t];
        s2 += pin[s * 2 * K + K + t];
      }
      float m   = s1 * invN;
      float var = s2 * invN - m * m;
      float scv = gw[t] * rsqrtf(var + BNEPS);
      sbn[t]     = scv;
      sbn[K + t] = bw[t] - m * scv;
    }
    __syncthreads();
  }
  for (int i = threadIdx.x; i < (K / 2) * F; i += 256) {
    int nn = i % F;
    int kk = (i / F) * 2;
    float w0 = W[(long long)kk * F + nn];
    float w1 = W[(long long)(kk + 1) * F + nn];
    *(unsigned*)&sWT[nn * SP + kk] = bfpack(w0, w1);
  }
  for (int i = threadIdx.x; i < 64 * (K / 8); i += 256) {
    int r = i / (K / 8), k8 = (i % (K / 8)) * 8;
    int gr = row0 + r;
    uint4 u = {0, 0, 0, 0};
    if (gr < n) {
      if constexpr (XBF) {
        const unsigned short* X = (const unsigned short*)Xv;
        uint4 raw = *(const uint4*)&X[(long long)gr * K + k8];
        if constexpr (BNIN) {
          float2 p0 = bfunpack(raw.x), p1 = bfunpack(raw.y);
          float2 p2 = bfunpack(raw.z), p3 = bfunpack(raw.w);
          float y[8] = {p0.x,p0.y,p1.x,p1.y,p2.x,p2.y,p3.x,p3.y};
#pragma unroll
          for (int j = 0; j < 8; j++) {
            float t = fmaf(y[j], sbn[k8 + j], sbn[K + k8 + j]);
            y[j] = (t >= 0.f) ? t : LEAK * t;
          }
          u.x = bfpack(y[0], y[1]); u.y = bfpack(y[2], y[3]);
          u.z = bfpack(y[4], y[5]); u.w = bfpack(y[6], y[7]);
        } else {
          u = raw;
        }
      } else {
        const float* X = (const float*)Xv;
        float4 xa = *(const float4*)&X[(long long)gr * K + k8];
        float4 xb = *(const float4*)&X[(long long)gr * K + k8 + 4];
        u.x = bfpack(xa.x, xa.y); u.y = bfpack(xa.z, xa.w);
        u.z = bfpack(xb.x, xb.y); u.w = bfpack(xb.z, xb.w);
      }
    }
    *(uint4*)&sX[r * SP + k8] = u;
  }
  __syncthreads();

  const int wv   = threadIdx.x >> 6;
  const int lane = threadIdx.x & 63;
  const int l16  = lane & 15;
  const int quad = lane >> 4;
  f32x4 acc[NCT];
#pragma unroll
  for (int c = 0; c < NCT; c++) acc[c] = (f32x4){0.f, 0.f, 0.f, 0.f};

#pragma unroll
  for (int k0 = 0; k0 < K; k0 += 32) {
    bf16x8 af = *(const bf16x8*)&sX[(wv * 16 + l16) * SP + k0 + quad * 8];
#pragma unroll
    for (int c = 0; c < NCT; c++) {
      bf16x8 bfr = *(const bf16x8*)&sWT[(c * 16 + l16) * SP + k0 + quad * 8];
      acc[c] = __builtin_amdgcn_mfma_f32_16x16x32_bf16(af, bfr, acc[c], 0, 0, 0);
    }
  }

  const int rbase = row0 + wv * 16 + quad * 4;
  float ps[4];
#pragma unroll
  for (int rg = 0; rg < 4; rg++) {
    int gr = rbase + rg;
    ps[rg] = (prescale && gr < n) ? prescale[gr] : 1.0f;
  }
#pragma unroll
  for (int c = 0; c < NCT; c++) {
    int col = c * 16 + l16;
#pragma unroll
    for (int rg = 0; rg < 4; rg++) {
      int gr = rbase + rg;
      if (gr < n) {
        float val = acc[c][rg] * ps[rg];
        Yb[(long long)gr * F + col] = bfround(val);
        if constexpr (F8OUT) Yf8[(long long)gr * F + col] = f32_to_fp8(val);
      }
    }
  }
}

// ==== SAGE dual MFMA GEMM (BN1+lrelu fused): t1=X'@Wl fp8, t2=X'@Wr+bl f32 ===
__global__ __launch_bounds__(256) void k_gemm_sage_mfma(
    const unsigned short* __restrict__ X, const float* __restrict__ Wl,
    const float* __restrict__ Wr, const float* __restrict__ bl,
    const float* __restrict__ pin, const float* __restrict__ gw,
    const float* __restrict__ bw, float invN,
    unsigned char* __restrict__ t1f8, float* __restrict__ t2,
    float* __restrict__ zptr, int zcnt, int n) {
  constexpr int K = 128, F = 64, SP = K + 8, NCT = F / 16;  // 4
  __shared__ unsigned short sX[64 * SP];
  __shared__ unsigned short sWlT[F * SP];
  __shared__ unsigned short sWrT[F * SP];
  __shared__ float sbn[2 * K];

  for (int i = blockIdx.x * 256 + threadIdx.x; i < zcnt; i += gridDim.x * 256)
    zptr[i] = 0.f;

  {
    int t = threadIdx.x;
    if (t < K) {
      float s1 = 0.f, s2 = 0.f;
      for (int s = 0; s < NSLOT; s++) {
        s1 += pin[s * 2 * K + t];
        s2 += pin[s * 2 * K + K + t];
      }
      float m   = s1 * invN;
      float var = s2 * invN - m * m;
      float scv = gw[t] * rsqrtf(var + BNEPS);
      sbn[t]     = scv;
      sbn[K + t] = bw[t] - m * scv;
    }
  }
  __syncthreads();
  const int row0 = blockIdx.x * 64;
  for (int i = threadIdx.x; i < (K / 2) * F; i += 256) {
    int nn = i % F;
    int kk = (i / F) * 2;
    *(unsigned*)&sWlT[nn * SP + kk] =
        bfpack(Wl[(long long)kk * F + nn], Wl[(long long)(kk + 1) * F + nn]);
    *(unsigned*)&sWrT[nn * SP + kk] =
        bfpack(Wr[(long long)kk * F + nn], Wr[(long long)(kk + 1) * F + nn]);
  }
  for (int i = threadIdx.x; i < 64 * (K / 8); i += 256) {
    int r = i / (K / 8), k8 = (i % (K / 8)) * 8;
    int gr = row0 + r;
    uint4 u = {0, 0, 0, 0};
    if (gr < n) {
      uint4 raw = *(const uint4*)&X[(long long)gr * K + k8];
      float2 p0 = bfunpack(raw.x), p1 = bfunpack(raw.y);
      float2 p2 = bfunpack(raw.z), p3 = bfunpack(raw.w);
      float y[8] = {p0.x,p0.y,p1.x,p1.y,p2.x,p2.y,p3.x,p3.y};
#pragma unroll
      for (int j = 0; j < 8; j++) {
        float t = fmaf(y[j], sbn[k8 + j], sbn[K + k8 + j]);
        y[j] = (t >= 0.f) ? t : LEAK * t;
      }
      u.x = bfpack(y[0], y[1]); u.y = bfpack(y[2], y[3]);
      u.z = bfpack(y[4], y[5]); u.w = bfpack(y[6], y[7]);
    }
    *(uint4*)&sX[r * SP + k8] = u;
  }
  __syncthreads();

  const int wv   = threadIdx.x >> 6;
  const int lane = threadIdx.x & 63;
  const int l16  = lane & 15;
  const int quad = lane >> 4;
  f32x4 a1[NCT], a2[NCT];
#pragma unroll
  for (int c = 0; c < NCT; c++) {
    a1[c] = (f32x4){0.f, 0.f, 0.f, 0.f};
    a2[c] = (f32x4){0.f, 0.f, 0.f, 0.f};
  }
#pragma unroll
  for (int k0 = 0; k0 < K; k0 += 32) {
    bf16x8 af = *(const bf16x8*)&sX[(wv * 16 + l16) * SP + k0 + quad * 8];
#pragma unroll
    for (int c = 0; c < NCT; c++) {
      bf16x8 bl8 = *(const bf16x8*)&sWlT[(c * 16 + l16) * SP + k0 + quad * 8];
      bf16x8 br8 = *(const bf16x8*)&sWrT[(c * 16 + l16) * SP + k0 + quad * 8];
      a1[c] = __builtin_amdgcn_mfma_f32_16x16x32_bf16(af, bl8, a1[c], 0, 0, 0);
      a2[c] = __builtin_amdgcn_mfma_f32_16x16x32_bf16(af, br8, a2[c], 0, 0, 0);
    }
  }
  const int rbase = row0 + wv * 16 + quad * 4;
#pragma unroll
  for (int c = 0; c < NCT; c++) {
    int col = c * 16 + l16;
    float blv = bl[col];
#pragma unroll
    for (int rg = 0; rg < 4; rg++) {
      int gr = rbase + rg;
      if (gr < n) {
        t1f8[(long long)gr * F + col] = f32_to_fp8(a1[c][rg]);
        t2[(long long)gr * F + col]   = a2[c][rg] + blv;
      }
    }
  }
}

// ---------------- link predictor ----------------
__global__ void k_link(const float* __restrict__ g, const int* __restrict__ li0,
                       const int* __restrict__ li1, float* __restrict__ out, int L) {
  int i = blockIdx.x * blockDim.x + threadIdx.x;
  if (i >= L) return;
  const float* a = g + (long long)li0[i] * 32;
  const float* b = g + (long long)li1[i] * 32;
  float s = 0.f;
#pragma unroll
  for (int f = 0; f < 32; f++) s = fmaf(a[f], b[f], s);
  out[i] = 1.0f / (1.0f + expf(-s));
}

// ---------------- launch ----------------
extern "C" void kernel_launch(void* const* d_in, const int* in_sizes, int n_in,
                              void* d_out, int out_size, void* d_ws, size_t ws_size,
                              hipStream_t stream) {
  const float* x   = (const float*)d_in[0];
  const int* ei    = (const int*)d_in[1];
  const int* batch = (const int*)d_in[2];
  const int* li    = (const int*)d_in[3];
  const float* W1  = (const float*)d_in[5];
  const float* b1  = (const float*)d_in[6];
  const float* g1  = (const float*)d_in[7];
  const float* be1 = (const float*)d_in[8];
  const float* Wl2 = (const float*)d_in[9];
  const float* bl2 = (const float*)d_in[10];
  const float* Wr2 = (const float*)d_in[11];
  const float* g2  = (const float*)d_in[12];
  const float* be2 = (const float*)d_in[13];
  const float* W3  = (const float*)d_in[14];
  const float* b3  = (const float*)d_in[15];
  const float* g3  = (const float*)d_in[16];
  const float* be3 = (const float*)d_in[17];
  const float* W4  = (const float*)d_in[18];
  const float* b4  = (const float*)d_in[19];

  const int n = in_sizes[0] / 128;   // 50000
  const int E = in_sizes[1] / 2;     // 800000
  const int L = in_sizes[3] / 2;     // 1000
  const int* src = ei;
  const int* dst = ei + E;
  const int* li0 = li;
  const int* li1 = li + L;
  const int NBK = (n + 255) / 256;   // dst buckets (<=256 for n<=65536)

  char* base = (char*)d_ws;
  size_t off = 0;
  auto alloc = [&](size_t bytes) -> void* {
    void* p = (void*)(base + off);
    off = (off + bytes + 255) & ~(size_t)255;
    return p;
  };
  int*   H      = (int*)alloc((size_t)NBK * NCH * 4);
  int*   O      = (int*)alloc((size_t)NBK * NCH * 4);
  int*   hsum   = (int*)alloc((size_t)1024 * 4);
  int*   ebuf   = (int*)alloc((size_t)E * 4);
  int*   eidx   = (int*)alloc((size_t)E * 4);
  int*   rowptr = (int*)alloc((size_t)(n + 1) * 4);
  float* dinv   = (float*)alloc((size_t)n * 4);
  float* invcnt = (float*)alloc((size_t)n * 4);
  float* partials1 = (float*)alloc((size_t)NSLOT * 256 * 4);  // layer1: 2F=256
  float* partials2 = (float*)alloc((size_t)NSLOT * 128 * 4);  // layer2: 2F=128
  float* partials3 = (float*)alloc((size_t)NSLOT * 64 * 4);   // layer3: 2F=64
  float* gpool  = (float*)alloc((size_t)NGMAX * 32 * 4);
  unsigned short* h1b  = (unsigned short*)alloc((size_t)n * 128 * 2); // dinv*(x@W1) bf16
  unsigned char*  h1f8 = (unsigned char*)alloc((size_t)n * 128);     // same, fp8 e4m3
  unsigned short* a1b  = (unsigned short*)alloc((size_t)n * 128 * 2); // pre-BN a1
  unsigned char*  t1f8 = (unsigned char*)alloc((size_t)n * 64);      // h1'@Wl2 fp8
  float*          t2f  = (float*)alloc((size_t)n * 64 * 4);          // h1'@Wr2+bl2
  unsigned short* h2b  = (unsigned short*)alloc((size_t)n * 64 * 2); // pre-BN h2
  unsigned short* h3gb = (unsigned short*)alloc((size_t)n * 32 * 2); // dinv*(h2'@W3)
  unsigned short* a3b  = (unsigned short*)alloc((size_t)n * 32 * 2); // pre-BN a3
  unsigned short* h4b  = (unsigned short*)alloc((size_t)n * 32 * 2); // dinv*(h3'@W4)
  (void)ws_size; (void)n_in; (void)out_size;

  const int BT = 256;
  auto cdiv = [](long long a, long long b) { return (int)((a + b - 1) / b); };
  const int GB  = cdiv(n, 4);                 // gather grid
  const int GM  = cdiv(n, 64);                // mfma gemm grid
  const int MH  = NBK * NCH;                  // histogram elements
  const int NBH = cdiv(MH, 256);              // scan blocks
  const float invN = 1.0f / (float)n;

  // ---- CSR build: bucketed counting sort ----
  k_hist<<<NCH, 256, 0, stream>>>(dst, H, E, NBK);
  k_gscan1<<<NBH, 256, 0, stream>>>(H, hsum, MH);
  k_gscan2<<<1, 256, 0, stream>>>(hsum, NBH);
  k_gscan3<<<NBH, 256, 0, stream>>>(H, hsum, O, MH);
  k_scatter_bkt<<<NCH, 256, 0, stream>>>(src, dst, O, ebuf, E, NBK);
  k_fill2<<<NBK, 256, 0, stream>>>(ebuf, O, eidx, rowptr, dinv, invcnt, E, n, NBK);

  // ---- L1: GCN 128->128 (MFMA; emits bf16 + fp8; zeroes partials1) ----
  k_gemm_mfma<128,128,false,false,true><<<GM, 256, 0, stream>>>(
      x, W1, nullptr, nullptr, nullptr, 0.f, dinv, h1b, h1f8,
      partials1, NSLOT * 256, n);
  k_gather<128,true,true,false,true,false><<<GB, 256, 0, stream>>>(
      h1f8, h1b, dinv, rowptr, eidx, b1, nullptr, a1b,
      partials1, nullptr, nullptr, n);

  // ---- L2: SAGE 128->64 (MFMA dual; BN1 finalized in-prologue) ----
  k_gemm_sage_mfma<<<GM, 256, 0, stream>>>(
      a1b, Wl2, Wr2, bl2, partials1, g1, be1, invN, t1f8, t2f,
      partials2, NSLOT * 128, n);
  k_gather<64,true,false,true,true,false><<<GB, 256, 0, stream>>>(
      t1f8, nullptr, invcnt, rowptr, eidx, nullptr, t2f, h2b,
      partials2, nullptr, nullptr, n);

  // ---- L3: GCN 64->32 (MFMA; BN2 finalized in-prologue) ----
  k_gemm_mfma<64,32,true,true,false><<<GM, 256, 0, stream>>>(
      h2b, W3, partials2, g2, be2, invN, dinv, h3gb, nullptr,
      partials3, NSLOT * 64, n);
  k_gather<32,false,true,false,true,false><<<GB, 256, 0, stream>>>(
      h3gb, h3gb, dinv, rowptr, eidx, b3, nullptr, a3b,
      partials3, nullptr, nullptr, n);

  // ---- L4: GCN 32->32 (MFMA; BN3 finalized in-prologue; zeroes gpool),
  //      gather pools directly via atomics into gpool ----
  k_gemm_mfma<32,32,true,true,false><<<GM, 256, 0, stream>>>(
      a3b, W4, partials3, g3, be3, invN, dinv, h4b, nullptr,
      gpool, NGMAX * 32, n);
  k_gather<32,false,true,false,false,true><<<GB, 256, 0, stream>>>(
      h4b, h4b, dinv, rowptr, eidx, b4, nullptr, nullptr,
      nullptr, batch, gpool, n);

  // ---- link ----
  k_link<<<cdiv(L, BT), BT, 0, stream>>>(gpool, li0, li1, (float*)d_out, L);
}